// Round 1
// baseline (721.054 us; speedup 1.0000x reference)
//
#include <hip/hip_runtime.h>
#include <hip/hip_bf16.h>
#include <math.h>

#define B_ 2
#define S_ 2048
#define D_ 2048
#define H_ 16
#define DK_ 128
#define DL_ 512
#define DR_ 64
#define BS_ (B_ * S_)   // 4096

typedef __attribute__((ext_vector_type(8))) short short8;
typedef __attribute__((ext_vector_type(4))) float f32x4;

static __device__ __forceinline__ ushort f2b(float f) {
    union { __hip_bfloat16 h; ushort u; } cvt;
    cvt.h = __float2bfloat16(f);
    return cvt.u;
}

#define GLOAD_LDS16(g, l)                                                         \
    __builtin_amdgcn_global_load_lds(                                             \
        (const __attribute__((address_space(1))) void*)(g),                       \
        (__attribute__((address_space(3))) void*)(l), 16, 0, 0)

// ---------------------------------------------------------------------------
// fp32 -> bf16 elementwise convert (n divisible by 4)
// ---------------------------------------------------------------------------
__global__ __launch_bounds__(256) void cvt_f32_bf16(const float* __restrict__ in,
                                                    ushort* __restrict__ out, int n) {
    int i = (blockIdx.x * 256 + threadIdx.x) * 4;
    if (i >= n) return;
    float4 v = *(const float4*)(in + i);
    ushort4 o;
    o.x = f2b(v.x); o.y = f2b(v.y); o.z = f2b(v.z); o.w = f2b(v.w);
    *(ushort4*)(out + i) = o;
}

// ---------------------------------------------------------------------------
// fp32 (R x C) -> bf16 transposed (C x R).  grid (C/32, R/32), block (32, 8)
// ---------------------------------------------------------------------------
__global__ __launch_bounds__(256) void transpose_cvt(const float* __restrict__ in,
                                                     ushort* __restrict__ out,
                                                     int R, int C) {
    __shared__ float tile[32][33];
    int c0 = blockIdx.x * 32, r0 = blockIdx.y * 32;
    int tx = threadIdx.x, ty = threadIdx.y;
#pragma unroll
    for (int i = 0; i < 4; ++i)
        tile[ty + i * 8][tx] = in[(size_t)(r0 + ty + i * 8) * C + c0 + tx];
    __syncthreads();
#pragma unroll
    for (int i = 0; i < 4; ++i)
        out[(size_t)(c0 + ty + i * 8) * R + r0 + tx] = f2b(tile[tx][ty + i * 8]);
}

// ---------------------------------------------------------------------------
// RoPE cos/sin tables, matches jnp: freq = (1e-4)^linspace(0,1,16) ++ zeros(16)
// grid 256 x 256 threads = S*32 entries
// ---------------------------------------------------------------------------
__global__ __launch_bounds__(256) void rope_tables(float* __restrict__ cosT,
                                                   float* __restrict__ sinT) {
    int idx = blockIdx.x * 256 + threadIdx.x;
    int s = idx >> 5, j = idx & 31;
    float c = 1.f, sn = 0.f;
    if (j < 16) {
        float t = (float)j * (1.0f / 15.0f);
        float f = powf(10000.0f, -t);
        float th = (float)s * f;
        c = cosf(th);
        sn = sinf(th);
    }
    cosT[idx] = c;
    sinT[idx] = sn;
}

// ---------------------------------------------------------------------------
// bf16 GEMM, A (MxK) row-major, BT (NxK) row-major, C = A*B (MxN).
// 128x128 tile, BK=32, 4 waves in 2x2, each wave 64x64 via 4x4 16x16 frags.
// m97 structure: global_load_lds width 16, single LDS buffer, 2 barriers.
// ---------------------------------------------------------------------------
template <int OUT_BF16>
__global__ __launch_bounds__(256) void gemm_bt(const ushort* __restrict__ A,
                                               const ushort* __restrict__ BT,
                                               void* __restrict__ Cv,
                                               int M, int N, int K) {
    __shared__ __align__(16) ushort As[128 * 32];
    __shared__ __align__(16) ushort Bs[128 * 32];
    const int tid = threadIdx.x;
    const int lane = tid & 63, wave = tid >> 6;
    const int wr = wave >> 1, wc = wave & 1;
    const int row0 = blockIdx.y * 128, col0 = blockIdx.x * 128;
    const int fr = lane & 15, kg = (lane >> 4) * 8;

    f32x4 acc[4][4] = {};

    // staging: idx = i*256 + tid ; row = idx>>2 ; col8 = (idx&3)*8 ; 16B per lane
    const int sr = tid >> 2;
    const int sc8 = (tid & 3) * 8;
    const ushort* ga = A + (size_t)(row0 + sr) * K + sc8;
    const ushort* gb = BT + (size_t)(col0 + sr) * K + sc8;
    ushort* asDst = As + (size_t)(wave * 64) * 8;   // lane*16B appended by HW
    ushort* bsDst = Bs + (size_t)(wave * 64) * 8;

    for (int k0 = 0; k0 < K; k0 += 32) {
        GLOAD_LDS16(ga + k0, asDst);
        GLOAD_LDS16(ga + (size_t)64 * K + k0, asDst + 256 * 8);
        GLOAD_LDS16(gb + k0, bsDst);
        GLOAD_LDS16(gb + (size_t)64 * K + k0, bsDst + 256 * 8);
        __syncthreads();

        short8 af[4], bfr[4];
#pragma unroll
        for (int m = 0; m < 4; ++m)
            af[m] = *(const short8*)&As[(wr * 64 + m * 16 + fr) * 32 + kg];
#pragma unroll
        for (int n = 0; n < 4; ++n)
            bfr[n] = *(const short8*)&Bs[(wc * 64 + n * 16 + fr) * 32 + kg];
#pragma unroll
        for (int m = 0; m < 4; ++m)
#pragma unroll
            for (int n = 0; n < 4; ++n)
                acc[m][n] = __builtin_amdgcn_mfma_f32_16x16x32_bf16(af[m], bfr[n],
                                                                    acc[m][n], 0, 0, 0);
        __syncthreads();
    }

    // C/D layout: col = lane&15, row = (lane>>4)*4 + j   [m89/m91 verified]
    const int rbase = row0 + wr * 64 + (lane >> 4) * 4;
    const int cbase = col0 + wc * 64 + fr;
    if constexpr (OUT_BF16) {
        ushort* C = (ushort*)Cv;
#pragma unroll
        for (int m = 0; m < 4; ++m)
#pragma unroll
            for (int n = 0; n < 4; ++n)
#pragma unroll
                for (int j = 0; j < 4; ++j)
                    C[(size_t)(rbase + m * 16 + j) * N + cbase + n * 16] = f2b(acc[m][n][j]);
    } else {
        float* C = (float*)Cv;
#pragma unroll
        for (int m = 0; m < 4; ++m)
#pragma unroll
            for (int n = 0; n < 4; ++n)
#pragma unroll
                for (int j = 0; j < 4; ++j)
                    C[(size_t)(rbase + m * 16 + j) * N + cbase + n * 16] = acc[m][n][j];
    }
}

// ---------------------------------------------------------------------------
// q: rmsnorm (over 128, weight) then RoPE on first 64 dims. 1 wave = 1 row.
// grid = B*S*H/4 blocks of 256
// ---------------------------------------------------------------------------
__global__ __launch_bounds__(256) void q_norm_rope(const float* __restrict__ qp,
                                                   const float* __restrict__ w,
                                                   const float* __restrict__ cosT,
                                                   const float* __restrict__ sinT,
                                                   ushort* __restrict__ qb) {
    const int lane = threadIdx.x & 63, wave = threadIdx.x >> 6;
    const int rowId = blockIdx.x * 4 + wave;
    const int bs = rowId >> 4, h = rowId & 15;
    const int s = bs & (S_ - 1);
    const float* src = qp + (size_t)bs * 2048 + h * 128;
    float e0 = src[lane], e1 = src[64 + lane];
    float ss = e0 * e0 + e1 * e1;
#pragma unroll
    for (int m = 1; m < 64; m <<= 1) ss += __shfl_xor(ss, m, 64);
    float r = rsqrtf(ss * (1.0f / 128.0f) + 1e-6f);
    float xn0 = e0 * r * w[lane];
    float xn1 = e1 * r * w[64 + lane];
    int j = lane & 31;
    float c = cosT[s * 32 + j], sn = sinT[s * 32 + j];
    float p = __shfl_xor(xn0, 32, 64);
    float y0 = (lane < 32) ? (xn0 * c + p * sn) : (-p * sn + xn0 * c);
    ushort* dst = qb + (size_t)bs * 2048 + h * 128;
    dst[lane] = f2b(y0);
    dst[64 + lane] = f2b(xn1);
}

// ---------------------------------------------------------------------------
// k: RoPE(k_rope) ++ k_nope, then rmsnorm over 128. 1 wave = 1 row.
// ---------------------------------------------------------------------------
__global__ __launch_bounds__(256) void k_assemble(const float* __restrict__ krp,
                                                  const float* __restrict__ knp,
                                                  const float* __restrict__ w,
                                                  const float* __restrict__ cosT,
                                                  const float* __restrict__ sinT,
                                                  ushort* __restrict__ kb) {
    const int lane = threadIdx.x & 63, wave = threadIdx.x >> 6;
    const int rowId = blockIdx.x * 4 + wave;
    const int bs = rowId >> 4, h = rowId & 15;
    const int s = bs & (S_ - 1);
    float e0 = krp[(size_t)bs * 1024 + h * 64 + lane];
    float e1 = knp[(size_t)bs * 1024 + h * 64 + lane];
    int j = lane & 31;
    float c = cosT[s * 32 + j], sn = sinT[s * 32 + j];
    float p = __shfl_xor(e0, 32, 64);
    float y0 = (lane < 32) ? (e0 * c + p * sn) : (-p * sn + e0 * c);
    float ss = y0 * y0 + e1 * e1;
#pragma unroll
    for (int m = 1; m < 64; m <<= 1) ss += __shfl_xor(ss, m, 64);
    float r = rsqrtf(ss * (1.0f / 128.0f) + 1e-6f);
    ushort* dst = kb + (size_t)bs * 2048 + h * 128;
    dst[lane] = f2b(y0 * r * w[lane]);
    dst[64 + lane] = f2b(e1 * r * w[64 + lane]);
}

// ---------------------------------------------------------------------------
// causal flash attention. grid (S/64, B*H), block 256 (4 waves x 16 q rows).
// KV tile = 32. Q,K,V,O all [B*S][H*128] bf16.
// ---------------------------------------------------------------------------
__global__ __launch_bounds__(256) void attn_fwd(const ushort* __restrict__ Q,
                                                const ushort* __restrict__ Kb,
                                                const ushort* __restrict__ Vb,
                                                ushort* __restrict__ Ob) {
    __shared__ __align__(16) ushort Vl[128 * 32];     // [d][k] transposed
    __shared__ __align__(16) ushort Pl[4][16 * 32];   // per-wave P
    const int tid = threadIdx.x, lane = tid & 63, wave = tid >> 6;
    const int bh = blockIdx.y, b = bh >> 4, h = bh & 15;
    const int q0 = blockIdx.x * 64;
    const int fr = lane & 15, kg = (lane >> 4) * 8;

    const ushort* qbase = Q + (size_t)(b * S_) * 2048 + h * 128;
    const ushort* kbase = Kb + (size_t)(b * S_) * 2048 + h * 128;
    const ushort* vbase = Vb + (size_t)(b * S_) * 2048 + h * 128;

    // Q fragments: row = lane&15 -> q0 + wave*16 + fr
    short8 qf[4];
    const ushort* qrow = qbase + (size_t)(q0 + wave * 16 + fr) * 2048;
#pragma unroll
    for (int kb = 0; kb < 4; ++kb) qf[kb] = *(const short8*)(qrow + kb * 32 + kg);

    f32x4 Oacc[8] = {};
    float mrow[4], lrow[4];
#pragma unroll
    for (int j = 0; j < 4; ++j) { mrow[j] = -1e30f; lrow[j] = 0.f; }
    const float scale = 0.08838834764831845f;  // 1/sqrt(128)
    const int ntiles = (q0 + 64) >> 5;

    for (int t = 0; t < ntiles; ++t) {
        const int kt0 = t * 32;
        // stage V transposed into LDS: Vl[d][k] = V[kt0+k][d]
        {
            const int kk = tid >> 3, db = (tid & 7) * 16;
            const ushort* vr = vbase + (size_t)(kt0 + kk) * 2048 + db;
            short8 v0 = *(const short8*)(vr);
            short8 v1 = *(const short8*)(vr + 8);
#pragma unroll
            for (int i = 0; i < 8; ++i) {
                Vl[(db + i) * 32 + kk] = (ushort)v0[i];
                Vl[(db + 8 + i) * 32 + kk] = (ushort)v1[i];
            }
        }
        // scores: 2 col-fragments of 16, K loaded straight from global (L2-hot)
        f32x4 sc[2] = {};
#pragma unroll
        for (int n = 0; n < 2; ++n) {
            const ushort* krow = kbase + (size_t)(kt0 + n * 16 + fr) * 2048;
#pragma unroll
            for (int kb = 0; kb < 4; ++kb) {
                short8 kf = *(const short8*)(krow + kb * 32 + kg);
                sc[n] = __builtin_amdgcn_mfma_f32_16x16x32_bf16(qf[kb], kf, sc[n], 0, 0, 0);
            }
        }
        // scale + causal mask + tile row-max
        float tmax[4];
#pragma unroll
        for (int j = 0; j < 4; ++j) tmax[j] = -1e30f;
#pragma unroll
        for (int n = 0; n < 2; ++n) {
            int kpos = kt0 + n * 16 + fr;
#pragma unroll
            for (int j = 0; j < 4; ++j) {
                int qr = q0 + wave * 16 + (lane >> 4) * 4 + j;
                float v = sc[n][j] * scale;
                v = (kpos <= qr) ? v : -1e30f;
                sc[n][j] = v;
                tmax[j] = fmaxf(tmax[j], v);
            }
        }
#pragma unroll
        for (int m = 1; m < 16; m <<= 1)
#pragma unroll
            for (int j = 0; j < 4; ++j) tmax[j] = fmaxf(tmax[j], __shfl_xor(tmax[j], m, 64));
        // online softmax update
        float alpha[4], rsum[4];
#pragma unroll
        for (int j = 0; j < 4; ++j) {
            float mn = fmaxf(mrow[j], tmax[j]);
            alpha[j] = __expf(mrow[j] - mn);
            mrow[j] = mn;
            rsum[j] = 0.f;
        }
#pragma unroll
        for (int n = 0; n < 2; ++n)
#pragma unroll
            for (int j = 0; j < 4; ++j) {
                float pv = __expf(sc[n][j] - mrow[j]);
                sc[n][j] = pv;
                rsum[j] += pv;
            }
#pragma unroll
        for (int m = 1; m < 16; m <<= 1)
#pragma unroll
            for (int j = 0; j < 4; ++j) rsum[j] += __shfl_xor(rsum[j], m, 64);
#pragma unroll
        for (int j = 0; j < 4; ++j) lrow[j] = lrow[j] * alpha[j] + rsum[j];
        // rescale O
#pragma unroll
        for (int n8 = 0; n8 < 8; ++n8)
#pragma unroll
            for (int j = 0; j < 4; ++j) Oacc[n8][j] *= alpha[j];
        // P -> LDS (per wave), layout [qrow16][k32]
#pragma unroll
        for (int n = 0; n < 2; ++n)
#pragma unroll
            for (int j = 0; j < 4; ++j)
                Pl[wave][((lane >> 4) * 4 + j) * 32 + n * 16 + fr] = f2b(sc[n][j]);
        __syncthreads();
        // PV: A = P (16x32), B = V (32x16 per d-group)
        short8 pa = *(const short8*)&Pl[wave][fr * 32 + kg];
#pragma unroll
        for (int n8 = 0; n8 < 8; ++n8) {
            short8 bv = *(const short8*)&Vl[(n8 * 16 + fr) * 32 + kg];
            Oacc[n8] = __builtin_amdgcn_mfma_f32_16x16x32_bf16(pa, bv, Oacc[n8], 0, 0, 0);
        }
        __syncthreads();
    }
    // epilogue: divide by l, store
#pragma unroll
    for (int j = 0; j < 4; ++j) {
        int qr = q0 + wave * 16 + (lane >> 4) * 4 + j;
        float inv = 1.0f / lrow[j];
        ushort* orow = Ob + (size_t)(b * S_ + qr) * 2048 + h * 128;
#pragma unroll
        for (int n8 = 0; n8 < 8; ++n8) orow[n8 * 16 + fr] = f2b(Oacc[n8][j] * inv);
    }
}

// ---------------------------------------------------------------------------
extern "C" void kernel_launch(void* const* d_in, const int* in_sizes, int n_in,
                              void* d_out, int out_size, void* d_ws, size_t ws_size,
                              hipStream_t stream) {
    (void)in_sizes; (void)n_in; (void)out_size; (void)ws_size;
    const float* x = (const float*)d_in[0];
    const float* wq = (const float*)d_in[1];
    const float* w_kv_down = (const float*)d_in[2];
    const float* w_k_rope = (const float*)d_in[3];
    const float* w_k_nope = (const float*)d_in[4];
    const float* wv = (const float*)d_in[5];
    const float* wo = (const float*)d_in[6];
    const float* q_norm_w = (const float*)d_in[7];
    const float* k_norm_w = (const float*)d_in[8];
    float* out = (float*)d_out;

    char* ws = (char*)d_ws;
    size_t off = 0;
    auto alloc = [&](size_t bytes) {
        off = (off + 255) & ~(size_t)255;
        void* p = ws + off;
        off += bytes;
        return p;
    };
    ushort* xb = (ushort*)alloc((size_t)BS_ * 2048 * 2);
    ushort* wq_t = (ushort*)alloc((size_t)2048 * 2048 * 2);
    ushort* wkv_t = (ushort*)alloc((size_t)512 * 2048 * 2);
    ushort* wkr_t = (ushort*)alloc((size_t)1024 * 512 * 2);
    ushort* wkn_t = (ushort*)alloc((size_t)1024 * 512 * 2);
    ushort* wv_t = (ushort*)alloc((size_t)2048 * 512 * 2);
    ushort* wo_t = (ushort*)alloc((size_t)2048 * 2048 * 2);
    float* q_pre = (float*)alloc((size_t)BS_ * 2048 * 4);
    ushort* latent_b = (ushort*)alloc((size_t)BS_ * 512 * 2);
    float* kr_pre = (float*)alloc((size_t)BS_ * 1024 * 4);
    float* kn_pre = (float*)alloc((size_t)BS_ * 1024 * 4);
    ushort* v_b = (ushort*)alloc((size_t)BS_ * 2048 * 2);
    ushort* q_b = (ushort*)alloc((size_t)BS_ * 2048 * 2);
    ushort* k_b = (ushort*)alloc((size_t)BS_ * 2048 * 2);
    ushort* ao_b = (ushort*)alloc((size_t)BS_ * 2048 * 2);
    float* cosT = (float*)alloc((size_t)S_ * 32 * 4);
    float* sinT = (float*)alloc((size_t)S_ * 32 * 4);

    // prep
    cvt_f32_bf16<<<(BS_ * 2048 / 4 + 255) / 256, 256, 0, stream>>>(x, xb, BS_ * 2048);
    transpose_cvt<<<dim3(2048 / 32, 2048 / 32), dim3(32, 8), 0, stream>>>(wq, wq_t, 2048, 2048);
    transpose_cvt<<<dim3(512 / 32, 2048 / 32), dim3(32, 8), 0, stream>>>(w_kv_down, wkv_t, 2048, 512);
    transpose_cvt<<<dim3(1024 / 32, 512 / 32), dim3(32, 8), 0, stream>>>(w_k_rope, wkr_t, 512, 1024);
    transpose_cvt<<<dim3(1024 / 32, 512 / 32), dim3(32, 8), 0, stream>>>(w_k_nope, wkn_t, 512, 1024);
    transpose_cvt<<<dim3(2048 / 32, 512 / 32), dim3(32, 8), 0, stream>>>(wv, wv_t, 512, 2048);
    transpose_cvt<<<dim3(2048 / 32, 2048 / 32), dim3(32, 8), 0, stream>>>(wo, wo_t, 2048, 2048);
    rope_tables<<<S_ * 32 / 256, 256, 0, stream>>>(cosT, sinT);

    // projections
    gemm_bt<0><<<dim3(2048 / 128, BS_ / 128), 256, 0, stream>>>(xb, wq_t, q_pre, BS_, 2048, 2048);
    gemm_bt<1><<<dim3(512 / 128, BS_ / 128), 256, 0, stream>>>(xb, wkv_t, latent_b, BS_, 512, 2048);
    gemm_bt<0><<<dim3(1024 / 128, BS_ / 128), 256, 0, stream>>>(latent_b, wkr_t, kr_pre, BS_, 1024, 512);
    gemm_bt<0><<<dim3(1024 / 128, BS_ / 128), 256, 0, stream>>>(latent_b, wkn_t, kn_pre, BS_, 1024, 512);
    gemm_bt<1><<<dim3(2048 / 128, BS_ / 128), 256, 0, stream>>>(latent_b, wv_t, v_b, BS_, 2048, 512);

    // norms + rope
    q_norm_rope<<<BS_ * H_ / 4, 256, 0, stream>>>(q_pre, q_norm_w, cosT, sinT, q_b);
    k_assemble<<<BS_ * H_ / 4, 256, 0, stream>>>(kr_pre, kn_pre, k_norm_w, cosT, sinT, k_b);

    // attention
    attn_fwd<<<dim3(S_ / 64, B_ * H_), 256, 0, stream>>>(q_b, k_b, v_b, ao_b);

    // output projection
    gemm_bt<0><<<dim3(2048 / 128, BS_ / 128), 256, 0, stream>>>(ao_b, wo_t, out, BS_, 2048, 2048);
}